// Round 7
// baseline (3721.116 us; speedup 1.0000x reference)
//
#include <hip/hip_runtime.h>

#define T_SEQ 512
#define HID 256

typedef _Float16 half8 __attribute__((ext_vector_type(8)));
typedef _Float16 half4 __attribute__((ext_vector_type(4)));
typedef float floatx4 __attribute__((ext_vector_type(4)));

// ws layout (f16 elements). Fragment = 64 lanes x 8 f16 = 512 elems.
// gh: [w8(8)][kt(8)][nt(6)] ; gi: [w8(8)][kt(2)][nt(6)] ; wb: [w8(8)][kt(8)][nt(2)] ; wd: [kt(8)]
#define OFF_GH 0
#define OFF_GI (OFF_GH + 384 * 512)
#define OFF_WB (OFF_GI + 96 * 512)
#define OFF_WD (OFF_WB + 128 * 512)

#define MFMA16(A, B, C) __builtin_amdgcn_mfma_f32_16x16x32_f16(A, B, C, 0, 0, 0)

__device__ __forceinline__ float sigm(float x) { return 1.0f / (1.0f + __expf(-x)); }
__device__ __forceinline__ float tanh_fast(float x) {
  float e = __expf(2.0f * x);
  return 1.0f - 2.0f / (e + 1.0f);
}

// Pack all weights (fp32 in) into f16 MFMA B-fragment order.
// B-frag for 16x16x32: lane l holds B[k=(l>>4)*8+j][n=l&15], value = W[n][k..k+7].
__global__ void prep_kernel(const float* __restrict__ w_ih,
                            const float* __restrict__ w_hh,
                            const float* __restrict__ w_base,
                            const float* __restrict__ w_dir,
                            const float* __restrict__ w_mag,
                            _Float16* __restrict__ ws) {
  const int f = blockIdx.x;
  const int lane = threadIdx.x;
  const int col = lane & 15, quad = lane >> 4;
  const float* src;
  int n, k, ld;
  _Float16* dst;
  if (f < 384) {  // w_hh frags: f = (w8*8 + kt)*6 + nt ; nt = gate*2 + s
    int nt = f % 6, kt = (f / 6) % 8, w = f / 48;
    n = (nt >> 1) * 256 + w * 32 + (nt & 1) * 16 + col;
    k = kt * 32 + quad * 8;
    src = w_hh; ld = 256;
    dst = ws + OFF_GH + ((w * 8 + kt) * 6 + nt) * 512 + lane * 8;
  } else if (f < 480) {  // w_ih frags
    int f2 = f - 384;
    int nt = f2 % 6, kt = (f2 / 6) % 2, w = f2 / 12;
    n = (nt >> 1) * 256 + w * 32 + (nt & 1) * 16 + col;
    k = kt * 32 + quad * 8;
    src = w_ih; ld = 64;
    dst = ws + OFF_GI + ((w * 2 + kt) * 6 + nt) * 512 + lane * 8;
  } else if (f < 608) {  // w_base frags
    int f3 = f - 480;
    int nt = f3 % 2, kt = (f3 / 2) % 8, w = f3 / 16;
    n = w * 32 + nt * 16 + col;
    k = kt * 32 + quad * 8;
    src = w_base; ld = 256;
    dst = ws + OFF_WB + ((w * 8 + kt) * 2 + nt) * 512 + lane * 8;
  } else {  // dir/mag combined: cols 0..7 dir, 8..15 mag
    int kt = f - 608;
    k = kt * 32 + quad * 8;
    ld = 256;
    if (col < 8) { src = w_dir; n = col; } else { src = w_mag; n = col - 8; }
    dst = ws + OFF_WD + kt * 512 + lane * 8;
  }
#pragma unroll
  for (int j = 0; j < 8; ++j)
    dst[j] = (_Float16)src[n * ld + k + j];
}

// 64 blocks x 1024 threads (16 waves, 4 waves/SIMD). Block owns 16 batch
// rows for all 512 steps. Wave w owns h-columns [16w,16w+16): 24 gh MFMAs
// (24 B-frags VGPR/AGPR-resident) + 6 gi MFMAs (6 B-frags in LDS) into 4
// accs (r, z, gh_n, gi_n). x per-lane register prefetch one step ahead.
// Epilogue: 4 elements/lane. h fp32 in registers; f16 shadow in LDS
// fragment-linear [kt][q][row][8]; one barrier per step.
__global__ __launch_bounds__(1024, 1)
void gru_head_kernel(const float* __restrict__ x_seq,
                     const float* __restrict__ b_ih,
                     const float* __restrict__ b_hh,
                     const float* __restrict__ b_base,
                     const float* __restrict__ b_dir,
                     const float* __restrict__ b_mag,
                     const _Float16* __restrict__ ws,
                     float* __restrict__ out) {
  __shared__ __align__(16) _Float16 hlin[2][4096];    // [kt(8)][q(4)][row(16)][8]
  __shared__ __align__(16) _Float16 wgi[16][6 * 512]; // gi B-frags per wave

  const int tid = threadIdx.x;
  const int lane = tid & 63;
  const int w = tid >> 6;       // wave 0..15
  const int col = lane & 15;
  const int quad = lane >> 4;
  const int row0 = blockIdx.x * 16;
  const int w8 = w >> 1, s = w & 1;

  // h0 = 0 (f16 shadow): 512 threads cover 4096 elements
  if (tid < 512) *(half8*)&hlin[0][tid * 8] = (half8)((_Float16)0.0f);

  // stage this wave's 6 gi B-frags into LDS (each wave touches only its own
  // region and reads only its own region -> no barrier needed for wgi)
  {
    const half8* gip = (const half8*)(ws + OFF_GI) + w8 * (12 * 64);
#pragma unroll
    for (int g = 0; g < 3; ++g)
#pragma unroll
      for (int kt = 0; kt < 2; ++kt) {
        const half8 v = gip[(kt * 6 + g * 2 + s) * 64 + lane];
        *(half8*)&wgi[w][(g * 2 + kt) * 512 + lane * 8] = v;
      }
  }

  // biases for this wave's columns c = 16w + col
  const int c = w * 16 + col;
  const float br = b_ih[c] + b_hh[c];
  const float bz = b_ih[256 + c] + b_hh[256 + c];
  const float bin_ = b_ih[512 + c];
  const float bhn = b_hh[512 + c];

  float hreg[4];
#pragma unroll
  for (int r2 = 0; r2 < 4; ++r2) hreg[r2] = 0.0f;

  // gh B-frags: frag(kt, g) = ghp[(kt*6 + g*2 + s)*64 + lane], VGPR/AGPR-resident
  const half8* __restrict__ ghp = (const half8*)(ws + OFF_GH) + w8 * (48 * 64);
  half8 wreg[24];
#pragma unroll
  for (int kt = 0; kt < 8; ++kt)
#pragma unroll
    for (int g = 0; g < 3; ++g)
      wreg[kt * 3 + g] = ghp[(kt * 6 + g * 2 + s) * 64 + lane];

  // per-lane x pointer: A[m=col][k=quad*8+j]
  const float* const xlane = x_seq + (size_t)(row0 + col) * (T_SEQ * 64) + quad * 8;

  // epilogue write index (col c -> hlin [kt=c>>5][q=(c&31)>>3][row][c&7])
  const int widx = w8 * 512 + ((s * 16 + col) >> 3) * 128 + (col & 7);

  float4 xc[4], xn[4];
  {
    const float* p = xlane;  // t = 0
    xc[0] = *(const float4*)(p);
    xc[1] = *(const float4*)(p + 4);
    xc[2] = *(const float4*)(p + 32);
    xc[3] = *(const float4*)(p + 36);
  }

  auto body = [&](int t, int tpre, int cur, float4* xcur, float4* xnext) {
    __syncthreads();
    const int nxt = cur ^ 1;

    // x prefetch for t+1 (full step of latency cover; drained at next barrier)
    {
      const float* p = xlane + (size_t)tpre * 64;
      xnext[0] = *(const float4*)(p);
      xnext[1] = *(const float4*)(p + 4);
      xnext[2] = *(const float4*)(p + 32);
      xnext[3] = *(const float4*)(p + 36);
    }

    // A-frags of h: 8 linear ds_read_b128
    half8 ah[8];
#pragma unroll
    for (int kt = 0; kt < 8; ++kt)
      ah[kt] = *(const half8*)&hlin[cur][kt * 512 + lane * 8];
    // gi B-frags from LDS (own region, linear)
    half8 wg[6];
#pragma unroll
    for (int j = 0; j < 6; ++j)
      wg[j] = *(const half8*)&wgi[w][j * 512 + lane * 8];

    // cvt current x -> f16 A-frags
    half8 ax0, ax1;
#pragma unroll
    for (int j = 0; j < 4; ++j) {
      ax0[j]     = (_Float16)((const float*)&xcur[0])[j];
      ax0[4 + j] = (_Float16)((const float*)&xcur[1])[j];
      ax1[j]     = (_Float16)((const float*)&xcur[2])[j];
      ax1[4 + j] = (_Float16)((const float*)&xcur[3])[j];
    }

    // accs: 0=r 1=z 2=gh_n 3=gi_n
    floatx4 acc[4];
#pragma unroll
    for (int a = 0; a < 4; ++a) acc[a] = (floatx4){0.f, 0.f, 0.f, 0.f};

    // 24 resident gh MFMAs
#pragma unroll
    for (int kt = 0; kt < 8; ++kt) {
      acc[0] = MFMA16(ah[kt], wreg[kt * 3 + 0], acc[0]);
      acc[1] = MFMA16(ah[kt], wreg[kt * 3 + 1], acc[1]);
      acc[2] = MFMA16(ah[kt], wreg[kt * 3 + 2], acc[2]);
    }
    // 6 gi MFMAs (wg layout: [g*2+kt])
    acc[0] = MFMA16(ax0, wg[0], acc[0]);
    acc[0] = MFMA16(ax1, wg[1], acc[0]);
    acc[1] = MFMA16(ax0, wg[2], acc[1]);
    acc[1] = MFMA16(ax1, wg[3], acc[1]);
    acc[3] = MFMA16(ax0, wg[4], acc[3]);
    acc[3] = MFMA16(ax1, wg[5], acc[3]);

    // epilogue: 4 elements (rows quad*4+r2, col c)
#pragma unroll
    for (int r2 = 0; r2 < 4; ++r2) {
      const float rr = sigm(acc[0][r2] + br);
      const float zz = sigm(acc[1][r2] + bz);
      const float nn = tanh_fast(acc[3][r2] + bin_ + rr * (acc[2][r2] + bhn));
      const float hnew = zz * hreg[r2] + (1.0f - zz) * nn;
      hreg[r2] = hnew;
      hlin[nxt][widx + (quad * 4 + r2) * 8] = (_Float16)hnew;
    }
  };

#pragma unroll 1
  for (int t = 0; t < T_SEQ; t += 2) {
    body(t, t + 1, 0, xc, xn);
    const int tp2 = (t + 2 < T_SEQ) ? (t + 2) : (T_SEQ - 1);
    body(t + 1, tp2, 1, xn, xc);
  }

  __syncthreads();
  // head: base = relu(hT @ w_base^T + b_base); h_T in hlin[0] (T even)
  // wave w computes base cols [16w, 16w+16)
  {
    const half8* wbp = (const half8*)(ws + OFF_WB) + (w8 * 16 + s) * 64;
    floatx4 ab = (floatx4){0.f, 0.f, 0.f, 0.f};
#pragma unroll
    for (int kt = 0; kt < 8; ++kt) {
      const half8 ahh = *(const half8*)&hlin[0][kt * 512 + lane * 8];
      ab = MFMA16(ahh, wbp[kt * 128 + lane], ab);
    }
    const float bb = b_base[c];
    __syncthreads();  // all reads of hlin[0] done before hlin[1] overwrite
#pragma unroll
    for (int r2 = 0; r2 < 4; ++r2) {
      const float v = ab[r2] + bb;
      hlin[1][widx + (quad * 4 + r2) * 8] = (_Float16)fmaxf(v, 0.0f);
    }
  }
  __syncthreads();

  // dir/mag heads: one N-tile (cols 0..7 = dir, 8..15 = mag), wave 0 only
  if (w == 0) {
    const half8* wdp = (const half8*)(ws + OFF_WD);
    floatx4 ad = (floatx4){0.f, 0.f, 0.f, 0.f};
#pragma unroll
    for (int kt = 0; kt < 8; ++kt) {
      const half8 ahh = *(const half8*)&hlin[1][kt * 512 + lane * 8];
      ad = MFMA16(ahh, wdp[kt * 64 + lane], ad);
    }
    const float bd = (col < 8) ? b_dir[col] : b_mag[col - 8];
#pragma unroll
    for (int r2 = 0; r2 < 4; ++r2) {
      const float v = ad[r2] + bd;
      const float act = (col < 8) ? tanh_fast(v) : sigm(v);
      const float other = __shfl_xor(act, 8, 64);
      if (col < 8)
        out[(size_t)(row0 + quad * 4 + r2) * 8 + col] = act * other;
    }
  }
}

extern "C" void kernel_launch(void* const* d_in, const int* in_sizes, int n_in,
                              void* d_out, int out_size, void* d_ws, size_t ws_size,
                              hipStream_t stream) {
  const float* x_seq  = (const float*)d_in[0];
  const float* b_ih   = (const float*)d_in[3];
  const float* b_hh   = (const float*)d_in[4];
  const float* b_base = (const float*)d_in[6];
  const float* b_dir  = (const float*)d_in[8];
  const float* b_mag  = (const float*)d_in[10];
  _Float16* ws = (_Float16*)d_ws;
  float* out = (float*)d_out;

  hipLaunchKernelGGL(prep_kernel, dim3(616), dim3(64), 0, stream,
                     (const float*)d_in[1], (const float*)d_in[2],
                     (const float*)d_in[5], (const float*)d_in[7],
                     (const float*)d_in[9], ws);
  hipLaunchKernelGGL(gru_head_kernel, dim3(64), dim3(1024), 0, stream,
                     x_seq, b_ih, b_hh, b_base, b_dir, b_mag, ws, out);
}